// Round 18
// baseline (56.924 us; speedup 1.0000x reference)
//
#include <hip/hip_runtime.h>
#include <math.h>

#define NB 4
#define NN 4096
#define QSCALE 0.1803368801f   // (1/sqrt(64)) * log2(e): scores in log2 domain

#define KS 16                  // key splits per q-tile
#define KPB 256                // keys per block chunk
#define STK 64                 // keys per supertile (8 KB staged)
#define NST (KPB / STK)        // 4 supertiles
#define NG 2                   // q-groups per wave (32 queries); q-tile = 128
#define NQT (NB * 32)          // q-tiles (128 queries each) = 128

typedef __bf16 bf16x8 __attribute__((ext_vector_type(8)));
typedef float f32x4 __attribute__((ext_vector_type(4)));
typedef float f32x2 __attribute__((ext_vector_type(2)));

union BF8 { unsigned short u[8]; bf16x8 v; uint4 q; };
union F2U { float2 f; unsigned long long u; };

static __device__ inline unsigned short f2bf(float f) {
    union { float f; unsigned u; } v; v.f = f;
    unsigned r = v.u + 0x7fffu + ((v.u >> 16) & 1u);   // RNE
    return (unsigned short)(r >> 16);
}

// async global->LDS, 16B per lane; dest = wave-uniform base + lane*16 (m104)
static __device__ inline void gload_lds16(const void* g, void* l) {
    __builtin_amdgcn_global_load_lds(
        (const __attribute__((address_space(1))) void*)g,
        (__attribute__((address_space(3))) void*)l, 16, 0, 0);
}

// ---------------------------------------------------------------------------
// Kernel 1: K + VW prep only (64 positions/block, 256 blocks). Each wave owns
// 16 positions, full d (4 ct x 2 MFMA). Block 0 zeroes finalize tickets.
// ---------------------------------------------------------------------------
__global__ __launch_bounds__(256) void prep_k(
    const float* __restrict__ x,
    const float* __restrict__ Wk, const float* __restrict__ bk,
    const float* __restrict__ Wv, const float* __restrict__ bv,
    const float* __restrict__ Wo,
    unsigned short* __restrict__ Kb, float* __restrict__ VW,
    int* __restrict__ tick)
{
    __shared__ float xt[64 * 66];                 // [c][n64], pad 66
    __shared__ float wve_s[64];
    __shared__ unsigned short rows[4][16 * 72];   // per-wave 16x72 bf16

    const int blk = blockIdx.x;                   // NB*64
    const int b = blk >> 6;
    const int n0 = (blk & 63) << 6;
    const int tid = threadIdx.x;
    const int wid = tid >> 6, lane = tid & 63;
    const int lg = lane >> 4, ll = lane & 15;

    if (blk == 0 && tid < NQT) tick[tid * 32] = 0;   // stream-ordered reset

    // x-tile: thread t -> row c=t>>2, cols (t&3)*16 + 0..15 (4x float4)
    {
        const int c = tid >> 2, nq = (tid & 3) * 16;
        const float* src = x + (size_t)b * 64 * NN + (size_t)c * NN + n0 + nq;
        #pragma unroll
        for (int i = 0; i < 4; ++i)
            *(float4*)&xt[c * 66 + nq + i * 4] = *(const float4*)(src + i * 4);
    }
    // wve[c] = sum_e Wo[e]*Wv[e*64+c], 4 lanes per c
    {
        int c = tid >> 2, part = tid & 3;
        float a = 0.f;
        #pragma unroll
        for (int j = 0; j < 16; ++j) {
            int e = part * 16 + j;
            a = fmaf(Wo[e], Wv[e * 64 + c], a);
        }
        a += __shfl_xor(a, 1);
        a += __shfl_xor(a, 2);
        if (part == 0) wve_s[c] = a;
    }
    float cv;
    {
        float p = Wo[lane] * bv[lane];
        #pragma unroll
        for (int off = 1; off < 64; off <<= 1) p += __shfl_xor(p, off);
        cv = p;
    }
    __syncthreads();

    // VW: 4 lanes per position (64 positions)
    {
        int pos = tid >> 2, part = tid & 3;
        float a = 0.f;
        #pragma unroll
        for (int j = 0; j < 16; ++j) {
            int c = part * 16 + j;
            a = fmaf(wve_s[c], xt[c * 66 + pos], a);
        }
        a += __shfl_xor(a, 1);
        a += __shfl_xor(a, 2);
        if (part == 0) VW[(size_t)b * NN + n0 + pos] = a + cv;
    }

    // A fragments: wave owns positions wid*16 + ll
    const int nr = wid * 16 + ll;
    BF8 a0, a1;
    #pragma unroll
    for (int j = 0; j < 8; ++j) {
        a0.v[j] = (__bf16)xt[(lg * 8 + j) * 66 + nr];
        a1.v[j] = (__bf16)xt[(32 + lg * 8 + j) * 66 + nr];
    }

    unsigned short* myrows = rows[wid];
    #pragma unroll
    for (int ct = 0; ct < 4; ++ct) {
        const float* wr = Wk + (ct * 16 + ll) * 64;
        float4 f0 = *(const float4*)(wr + lg * 8);
        float4 f1 = *(const float4*)(wr + lg * 8 + 4);
        float4 f2 = *(const float4*)(wr + 32 + lg * 8);
        float4 f3 = *(const float4*)(wr + 32 + lg * 8 + 4);
        BF8 w0, w1;
        w0.v[0] = (__bf16)f0.x; w0.v[1] = (__bf16)f0.y; w0.v[2] = (__bf16)f0.z; w0.v[3] = (__bf16)f0.w;
        w0.v[4] = (__bf16)f1.x; w0.v[5] = (__bf16)f1.y; w0.v[6] = (__bf16)f1.z; w0.v[7] = (__bf16)f1.w;
        w1.v[0] = (__bf16)f2.x; w1.v[1] = (__bf16)f2.y; w1.v[2] = (__bf16)f2.z; w1.v[3] = (__bf16)f2.w;
        w1.v[4] = (__bf16)f3.x; w1.v[5] = (__bf16)f3.y; w1.v[6] = (__bf16)f3.z; w1.v[7] = (__bf16)f3.w;
        f32x4 acc = {0.f, 0.f, 0.f, 0.f};
        acc = __builtin_amdgcn_mfma_f32_16x16x32_bf16(a0.v, w0.v, acc, 0, 0, 0);
        acc = __builtin_amdgcn_mfma_f32_16x16x32_bf16(a1.v, w1.v, acc, 0, 0, 0);
        float bias = bk[ct * 16 + ll];
        #pragma unroll
        for (int r = 0; r < 4; ++r)
            myrows[(lg * 4 + r) * 72 + ct * 16 + ll] = f2bf(acc[r] + bias);
    }
    // wave-local transpose readback: 4 lanes per position, 2x 16B each
    {
        int pos = lane >> 2, seg = lane & 3;
        const uint4* sp = (const uint4*)&myrows[pos * 72 + seg * 16];
        uint4 v0 = sp[0], v1 = sp[1];
        uint4* dst = (uint4*)(Kb + ((size_t)b * NN + n0 + wid * 16 + pos) * 64 + seg * 16);
        dst[0] = v0; dst[1] = v1;
    }
}

// ---------------------------------------------------------------------------
// Kernel 2: fused Q-proj + MFMA attention + relaxed-ticket finalize.
// Q-tile (128 queries) projected in-block from x (2 half-tiles through the
// kbuf LDS region, prep MFMA pattern, bit-identical math). Attention =
// R17 structure (gl_lds staging, XOR swizzle, packed (Z,A)). Finalize =
// RELAXED agent atomics only: __syncthreads' vmcnt drain orders partial
// stores before the ticket RMW; all atomics meet at die-level L3.
// ---------------------------------------------------------------------------
__global__ __launch_bounds__(256) void attn_fused(
    const float* __restrict__ x,
    const float* __restrict__ Wq, const float* __restrict__ bq,
    const unsigned short* __restrict__ Kb, const float* __restrict__ VW,
    const float* __restrict__ bo,
    float2* __restrict__ P2, int* __restrict__ tick, float* __restrict__ out)
{
    __shared__ __attribute__((aligned(16))) char Xregion[64 * 66 * 4]; // 16896 B
    __shared__ unsigned short rowsb[4][16 * 72];   // 9216 B
    __shared__ float vws[KPB];                     // 1 KB
    __shared__ int lastflag;
    float* xh = (float*)Xregion;                   // Q-proj x half-tile
    const int blk = blockIdx.x;                // ((b*32 + qt)*KS + ks)
    const int ks = blk & (KS - 1);
    const int t = blk >> 4;                    // q-tile 0..127
    const int b = t >> 5;
    const int q0 = (t & 31) << 7;              // 128-query tile
    const int tid = threadIdx.x;
    const int wid = tid >> 6, lane = tid & 63;
    const int lg = lane >> 4, ll = lane & 15;

    vws[tid] = VW[(size_t)b * NN + ks * KPB + tid];

    // ---- Q projection: 2 halves of 64 queries; wave wid computes its own
    // 16 queries (wid*16+ll) per half -> qfa[h], qfb[h]
    bf16x8 qfa[NG], qfb[NG];
    #pragma unroll 1
    for (int h = 0; h < NG; ++h) {
        {   // stage x half-tile [64 c][64 n]
            const int c = tid >> 2, nq = (tid & 3) * 16;
            const float* src = x + (size_t)b * 64 * NN + (size_t)c * NN
                               + q0 + h * 64 + nq;
            #pragma unroll
            for (int i = 0; i < 4; ++i)
                *(float4*)&xh[c * 66 + nq + i * 4] = *(const float4*)(src + i * 4);
        }
        __syncthreads();
        BF8 a0, a1;
        #pragma unroll
        for (int j = 0; j < 8; ++j) {
            a0.v[j] = (__bf16)xh[(lg * 8 + j) * 66 + wid * 16 + ll];
            a1.v[j] = (__bf16)xh[(32 + lg * 8 + j) * 66 + wid * 16 + ll];
        }
        unsigned short* myrows = rowsb[wid];
        #pragma unroll
        for (int ct = 0; ct < 4; ++ct) {
            const float* wr = Wq + (ct * 16 + ll) * 64;
            float4 f0 = *(const float4*)(wr + lg * 8);
            float4 f1 = *(const float4*)(wr + lg * 8 + 4);
            float4 f2 = *(const float4*)(wr + 32 + lg * 8);
            float4 f3 = *(const float4*)(wr + 32 + lg * 8 + 4);
            BF8 w0, w1;
            w0.v[0] = (__bf16)f0.x; w0.v[1] = (__bf16)f0.y; w0.v[2] = (__bf16)f0.z; w0.v[3] = (__bf16)f0.w;
            w0.v[4] = (__bf16)f1.x; w0.v[5] = (__bf16)f1.y; w0.v[6] = (__bf16)f1.z; w0.v[7] = (__bf16)f1.w;
            w1.v[0] = (__bf16)f2.x; w1.v[1] = (__bf16)f2.y; w1.v[2] = (__bf16)f2.z; w1.v[3] = (__bf16)f2.w;
            w1.v[4] = (__bf16)f3.x; w1.v[5] = (__bf16)f3.y; w1.v[6] = (__bf16)f3.z; w1.v[7] = (__bf16)f3.w;
            f32x4 acc = {0.f, 0.f, 0.f, 0.f};
            acc = __builtin_amdgcn_mfma_f32_16x16x32_bf16(a0.v, w0.v, acc, 0, 0, 0);
            acc = __builtin_amdgcn_mfma_f32_16x16x32_bf16(a1.v, w1.v, acc, 0, 0, 0);
            float bias = bq[ct * 16 + ll];
            #pragma unroll
            for (int r = 0; r < 4; ++r)
                myrows[(lg * 4 + r) * 72 + ct * 16 + ll] = f2bf((acc[r] + bias) * QSCALE);
        }
        // read own fragments (wave-local; compiler inserts lgkm waits)
        qfa[h] = *(const bf16x8*)&myrows[ll * 72 + lg * 8];
        qfb[h] = *(const bf16x8*)&myrows[ll * 72 + 32 + lg * 8];
        __syncthreads();   // xh free for next half / kbuf
    }

    // ---- attention: K staged via gl_lds into Xregion (2 x 8 KB dbuf)
    unsigned short* kbuf0 = (unsigned short*)Xregion;
    unsigned short* kbuf1 = (unsigned short*)(Xregion + 8192);
    const char* kchunk = (const char*)(Kb + ((size_t)b * NN + ks * KPB) * 64);
    const int lbase0 = wid * 1024;                 // bytes, wave-uniform
    const int lbase1 = lbase0 + 4096;
    const int lin0 = lbase0 + (lane << 4);
    const int g0 = lin0 ^ (((lin0 >> 7) & 7) << 4);
    const int g1 = g0 + 4096;
    const int c0 = (lg ^ (ll & 7)) & 7;
    const int c1 = ((lg + 4) ^ (ll & 7)) & 7;

    {   // prologue: stage supertile 0 into buf 0
        gload_lds16(kchunk + g0, (char*)kbuf0 + lbase0);
        gload_lds16(kchunk + g1, (char*)kbuf0 + lbase1);
    }
    __syncthreads();

    f32x2 ZA[NG];
    #pragma unroll
    for (int g = 0; g < NG; ++g) ZA[g] = (f32x2){0.f, 0.f};

    int cur = 0;
    #pragma unroll 1
    for (int st = 0; st < NST; ++st) {
        const bool more = (st + 1 < NST);
        if (more) {
            const char* src = kchunk + (size_t)(st + 1) * 8192;
            char* nb = (char*)(cur ? kbuf0 : kbuf1);
            gload_lds16(src + g0, nb + lbase0);
            gload_lds16(src + g1, nb + lbase1);
        }
        const char* kb = (const char*)(cur ? kbuf1 : kbuf0);
        #pragma unroll
        for (int kt = 0; kt < 4; ++kt) {
            const int rowb = (kt * 16 + ll) * 128;
            const bf16x8 k0 = *(const bf16x8*)(kb + rowb + (c0 << 4));
            const bf16x8 k1 = *(const bf16x8*)(kb + rowb + (c1 << 4));
            const float4 vv = *(const float4*)&vws[st * 64 + kt * 16 + lg * 4];
            const f32x2 w0 = {1.f, vv.x}, w1 = {1.f, vv.y};
            const f32x2 w2 = {1.f, vv.z}, w3 = {1.f, vv.w};
            #pragma unroll
            for (int g = 0; g < NG; ++g) {
                f32x4 acc = {0.f, 0.f, 0.f, 0.f};
                acc = __builtin_amdgcn_mfma_f32_16x16x32_bf16(k0, qfa[g], acc, 0, 0, 0);
                acc = __builtin_amdgcn_mfma_f32_16x16x32_bf16(k1, qfb[g], acc, 0, 0, 0);
                float e0 = __builtin_amdgcn_exp2f(acc[0]);
                float e1 = __builtin_amdgcn_exp2f(acc[1]);
                float e2 = __builtin_amdgcn_exp2f(acc[2]);
                float e3 = __builtin_amdgcn_exp2f(acc[3]);
                ZA[g] = __builtin_elementwise_fma((f32x2){e0, e0}, w0, ZA[g]);
                ZA[g] = __builtin_elementwise_fma((f32x2){e1, e1}, w1, ZA[g]);
                ZA[g] = __builtin_elementwise_fma((f32x2){e2, e2}, w2, ZA[g]);
                ZA[g] = __builtin_elementwise_fma((f32x2){e3, e3}, w3, ZA[g]);
            }
        }
        if (more) {
            __syncthreads();
            cur ^= 1;
        }
    }

    // ---- publish partial (relaxed agent atomics -> L3)
    #pragma unroll
    for (int g = 0; g < NG; ++g) {
        float Z = ZA[g].x, A = ZA[g].y;
        Z += __shfl_xor(Z, 16); Z += __shfl_xor(Z, 32);
        A += __shfl_xor(A, 16); A += __shfl_xor(A, 32);
        if (lg == 0) {
            F2U u; u.f = make_float2(Z, A);
            __hip_atomic_store(
                (unsigned long long*)&P2[((size_t)t * KS + ks) * 128 + g * 64 + wid * 16 + ll],
                u.u, __ATOMIC_RELAXED, __HIP_MEMORY_SCOPE_AGENT);
        }
    }
    __syncthreads();   // implicit vmcnt(0): partial stores COMPLETE here
    if (tid == 0) {
        int old = __hip_atomic_fetch_add(&tick[t * 32], 1, __ATOMIC_RELAXED,
                                         __HIP_MEMORY_SCOPE_AGENT);
        lastflag = (old == KS - 1);
    }
    __syncthreads();

    if (lastflag && tid < 128) {
        float Z = 0.f, A = 0.f;
        #pragma unroll
        for (int r = 0; r < KS; ++r) {
            F2U u;
            u.u = __hip_atomic_load(
                (unsigned long long*)&P2[((size_t)t * KS + r) * 128 + tid],
                __ATOMIC_RELAXED, __HIP_MEMORY_SCOPE_AGENT);
            Z += u.f.x; A += u.f.y;
        }
        float y = A / Z + bo[0];
        out[(size_t)b * NN + q0 + tid] = 1.f / (1.f + __expf(-y));
    }
}

extern "C" void kernel_launch(void* const* d_in, const int* in_sizes, int n_in,
                              void* d_out, int out_size, void* d_ws, size_t ws_size,
                              hipStream_t stream)
{
    const float* x  = (const float*)d_in[0];
    const float* Wq = (const float*)d_in[1];
    const float* bq = (const float*)d_in[2];
    const float* Wk = (const float*)d_in[3];
    const float* bk = (const float*)d_in[4];
    const float* Wv = (const float*)d_in[5];
    const float* bv = (const float*)d_in[6];
    const float* Wo = (const float*)d_in[7];
    const float* bo = (const float*)d_in[8];
    float* out = (float*)d_out;

    unsigned short* Kb = (unsigned short*)d_ws;            // 2 MB
    float* VW = (float*)(Kb + (size_t)NB * NN * 64);       // 64 KB
    float2* P2 = (float2*)(VW + (size_t)NB * NN);          // 2 MB
    int* tick = (int*)(P2 + (size_t)NQT * KS * 128);       // 16 KB (128B stride)

    prep_k<<<NB * 64, 256, 0, stream>>>(x, Wk, bk, Wv, bv, Wo, Kb, VW, tick);
    attn_fused<<<NQT * KS, 256, 0, stream>>>(x, Wq, bq, Kb, VW, bo, P2, tick, out);
}

// Round 19
// 33.323 us; speedup vs baseline: 1.7083x; 1.7083x over previous
//
#include <hip/hip_runtime.h>
#include <math.h>

#define NB 4
#define NN 4096
#define QSCALE 0.1803368801f   // (1/sqrt(64)) * log2(e): scores in log2 domain

#define KS 16                  // key splits per q-tile
#define KPB 256                // keys per block chunk
#define STK 64                 // keys per supertile (8 KB staged)
#define NST (KPB / STK)        // 4 supertiles
#define NG 2                   // q-groups per wave (32 queries); q-tile = 128
#define NQT (NB * 32)          // q-tiles (128 queries each) = 128

typedef __bf16 bf16x8 __attribute__((ext_vector_type(8)));
typedef float f32x4 __attribute__((ext_vector_type(4)));
typedef float f32x2 __attribute__((ext_vector_type(2)));

union BF8 { unsigned short u[8]; bf16x8 v; uint4 q; };

static __device__ inline unsigned short f2bf(float f) {
    union { float f; unsigned u; } v; v.f = f;
    unsigned r = v.u + 0x7fffu + ((v.u >> 16) & 1u);   // RNE
    return (unsigned short)(r >> 16);
}

// ---------------------------------------------------------------------------
// Kernel 1 (MFMA prep, 32 positions/block, 512 blocks) — R14's version.
// ---------------------------------------------------------------------------
__global__ __launch_bounds__(256) void prep_mfma(
    const float* __restrict__ x,
    const float* __restrict__ Wq, const float* __restrict__ bq,
    const float* __restrict__ Wk, const float* __restrict__ bk,
    const float* __restrict__ Wv, const float* __restrict__ bv,
    const float* __restrict__ Wo,
    unsigned short* __restrict__ Qb, unsigned short* __restrict__ Kb,
    float* __restrict__ VW)
{
    __shared__ float xt[64 * 33];                 // [c][n], n-pad 33
    __shared__ float wve_s[64];
    __shared__ unsigned short rows[4 * 16 * 72];  // per-wave 16x72 bf16

    const int blk = blockIdx.x;                   // NB*128
    const int b = blk >> 7;
    const int n0 = (blk & 127) << 5;
    const int tid = threadIdx.x;
    const int wid = tid >> 6, lane = tid & 63;
    const int lg = lane >> 4, ll = lane & 15;

    const float* xb = x + (size_t)b * 64 * NN;
    #pragma unroll
    for (int it = 0; it < 8; ++it) {
        int idx = it * 256 + tid;
        int c = idx >> 5, n = idx & 31;
        xt[c * 33 + n] = xb[(size_t)c * NN + n0 + n];
    }
    {
        int c = tid >> 2, part = tid & 3;
        float a = 0.f;
        #pragma unroll
        for (int j = 0; j < 16; ++j) {
            int e = part * 16 + j;
            a = fmaf(Wo[e], Wv[e * 64 + c], a);
        }
        a += __shfl_xor(a, 1);
        a += __shfl_xor(a, 2);
        if (part == 0) wve_s[c] = a;
    }
    float cv;
    {
        float p = Wo[lane] * bv[lane];
        #pragma unroll
        for (int off = 1; off < 64; off <<= 1) p += __shfl_xor(p, off);
        cv = p;
    }
    __syncthreads();

    {
        int nrel = tid >> 3, part = tid & 7;
        float a = 0.f;
        #pragma unroll
        for (int j = 0; j < 8; ++j) {
            int c = part * 8 + j;
            a = fmaf(wve_s[c], xt[c * 33 + nrel], a);
        }
        a += __shfl_xor(a, 1);
        a += __shfl_xor(a, 2);
        a += __shfl_xor(a, 4);
        if (part == 0) VW[(size_t)b * NN + n0 + nrel] = a + cv;
    }

    const int nr = (wid & 1) * 16 + ll;
    BF8 a0, a1;
    #pragma unroll
    for (int j = 0; j < 8; ++j) {
        a0.v[j] = (__bf16)xt[(lg * 8 + j) * 33 + nr];
        a1.v[j] = (__bf16)xt[(32 + lg * 8 + j) * 33 + nr];
    }

    const float* W  = (wid < 2) ? Wq : Wk;
    const float* bs = (wid < 2) ? bq : bk;
    unsigned short* Out = (wid < 2) ? Qb : Kb;
    const float scale = (wid < 2) ? QSCALE : 1.f;
    unsigned short* myrows = rows + wid * (16 * 72);

    #pragma unroll
    for (int ct = 0; ct < 4; ++ct) {
        const float* wr = W + (ct * 16 + ll) * 64;
        float4 f0 = *(const float4*)(wr + lg * 8);
        float4 f1 = *(const float4*)(wr + lg * 8 + 4);
        float4 f2 = *(const float4*)(wr + 32 + lg * 8);
        float4 f3 = *(const float4*)(wr + 32 + lg * 8 + 4);
        BF8 w0, w1;
        w0.v[0] = (__bf16)f0.x; w0.v[1] = (__bf16)f0.y; w0.v[2] = (__bf16)f0.z; w0.v[3] = (__bf16)f0.w;
        w0.v[4] = (__bf16)f1.x; w0.v[5] = (__bf16)f1.y; w0.v[6] = (__bf16)f1.z; w0.v[7] = (__bf16)f1.w;
        w1.v[0] = (__bf16)f2.x; w1.v[1] = (__bf16)f2.y; w1.v[2] = (__bf16)f2.z; w1.v[3] = (__bf16)f2.w;
        w1.v[4] = (__bf16)f3.x; w1.v[5] = (__bf16)f3.y; w1.v[6] = (__bf16)f3.z; w1.v[7] = (__bf16)f3.w;
        f32x4 acc = {0.f, 0.f, 0.f, 0.f};
        acc = __builtin_amdgcn_mfma_f32_16x16x32_bf16(a0.v, w0.v, acc, 0, 0, 0);
        acc = __builtin_amdgcn_mfma_f32_16x16x32_bf16(a1.v, w1.v, acc, 0, 0, 0);
        float bias = bs[ct * 16 + ll];
        #pragma unroll
        for (int r = 0; r < 4; ++r)
            myrows[(lg * 4 + r) * 72 + ct * 16 + ll] = f2bf((acc[r] + bias) * scale);
    }
    {
        int n = lane >> 2, c16 = lane & 3;
        const uint4* sp = (const uint4*)&myrows[n * 72 + c16 * 16];
        uint4 v0 = sp[0], v1 = sp[1];
        uint4* dst = (uint4*)(Out + ((size_t)b * NN + n0 + (wid & 1) * 16 + n) * 64 + c16 * 16);
        dst[0] = v0; dst[1] = v1;
    }
}

// ---------------------------------------------------------------------------
// Kernel 2: MFMA attention (R14 structure: KS=16, NG=2, LDS dbuf, packed
// (Z,A) pk_fma, 16B XOR swizzle write+read) + T5 s_setprio around the MFMA
// pair (blocks sit at different supertile phases -> scheduler has roles to
// arbitrate; the one catalog lever untested on this base).
// ---------------------------------------------------------------------------
__global__ __launch_bounds__(256) void attn_mfma(
    const unsigned short* __restrict__ Qb, const unsigned short* __restrict__ Kb,
    const float* __restrict__ VW, float2* __restrict__ P2)
{
    __shared__ unsigned short kbuf[2][STK * 64];   // 2 x 8 KB, swizzled
    __shared__ float vws[KPB];                     // 1 KB
    const int blk = blockIdx.x;                // ((b*32 + qt)*KS + ks)
    const int ks = blk & (KS - 1);
    const int t = blk >> 4;                    // 0..127
    const int b = t >> 5;
    const int q0 = (t & 31) << 7;              // 128-query tile
    const int tid = threadIdx.x;
    const int wid = tid >> 6, lane = tid & 63;
    const int lg = lane >> 4, ll = lane & 15;

    vws[tid] = VW[(size_t)b * NN + ks * KPB + tid];

    bf16x8 qfa[NG], qfb[NG];
    #pragma unroll
    for (int g = 0; g < NG; ++g) {
        const unsigned short* qp =
            Qb + ((size_t)b * NN + q0 + g * 64 + wid * 16 + ll) * 64 + lg * 8;
        qfa[g] = *(const bf16x8*)qp;
        qfb[g] = *(const bf16x8*)(qp + 32);
    }

    const char* kchunk = (const char*)(Kb + ((size_t)b * NN + ks * KPB) * 64);
    const int d0 = tid * 16, d1 = 4096 + tid * 16;
    const int sw0 = d0 ^ (((d0 >> 7) & 7) << 4);
    const int sw1 = d1 ^ (((d1 >> 7) & 7) << 4);
    const int c0 = (lg ^ (ll & 7)) & 7;
    const int c1 = ((lg + 4) ^ (ll & 7)) & 7;

    {   // prologue: stage supertile 0 into buf 0
        uint4 r0 = *(const uint4*)(kchunk + d0);
        uint4 r1 = *(const uint4*)(kchunk + d1);
        *(uint4*)((char*)kbuf[0] + sw0) = r0;
        *(uint4*)((char*)kbuf[0] + sw1) = r1;
    }
    __syncthreads();

    f32x2 ZA[NG];
    #pragma unroll
    for (int g = 0; g < NG; ++g) ZA[g] = (f32x2){0.f, 0.f};

    int cur = 0;
    #pragma unroll 1
    for (int st = 0; st < NST; ++st) {
        uint4 r0, r1;
        const bool more = (st + 1 < NST);
        if (more) {   // issue next-supertile loads EARLY (hide under compute)
            const char* src = kchunk + (size_t)(st + 1) * 8192;
            r0 = *(const uint4*)(src + d0);
            r1 = *(const uint4*)(src + d1);
        }
        const char* kb = (const char*)kbuf[cur];
        #pragma unroll
        for (int kt = 0; kt < 4; ++kt) {
            const int rowb = (kt * 16 + ll) * 128;
            const bf16x8 k0 = *(const bf16x8*)(kb + rowb + (c0 << 4));
            const bf16x8 k1 = *(const bf16x8*)(kb + rowb + (c1 << 4));
            const float4 vv = *(const float4*)&vws[st * 64 + kt * 16 + lg * 4];
            const f32x2 w0 = {1.f, vv.x}, w1 = {1.f, vv.y};
            const f32x2 w2 = {1.f, vv.z}, w3 = {1.f, vv.w};
            #pragma unroll
            for (int g = 0; g < NG; ++g) {
                __builtin_amdgcn_s_setprio(1);
                f32x4 acc = {0.f, 0.f, 0.f, 0.f};
                acc = __builtin_amdgcn_mfma_f32_16x16x32_bf16(k0, qfa[g], acc, 0, 0, 0);
                acc = __builtin_amdgcn_mfma_f32_16x16x32_bf16(k1, qfb[g], acc, 0, 0, 0);
                __builtin_amdgcn_s_setprio(0);
                float e0 = __builtin_amdgcn_exp2f(acc[0]);
                float e1 = __builtin_amdgcn_exp2f(acc[1]);
                float e2 = __builtin_amdgcn_exp2f(acc[2]);
                float e3 = __builtin_amdgcn_exp2f(acc[3]);
                ZA[g] = __builtin_elementwise_fma((f32x2){e0, e0}, w0, ZA[g]);
                ZA[g] = __builtin_elementwise_fma((f32x2){e1, e1}, w1, ZA[g]);
                ZA[g] = __builtin_elementwise_fma((f32x2){e2, e2}, w2, ZA[g]);
                ZA[g] = __builtin_elementwise_fma((f32x2){e3, e3}, w3, ZA[g]);
            }
        }
        if (more) {   // write-late into the other buffer, then one barrier
            char* dst = (char*)kbuf[cur ^ 1];
            *(uint4*)(dst + sw0) = r0;
            *(uint4*)(dst + sw1) = r1;
            __syncthreads();
            cur ^= 1;
        }
    }

    // reduce the 4 lane-groups (keys split across lg) for each query
    #pragma unroll
    for (int g = 0; g < NG; ++g) {
        float Z = ZA[g].x, A = ZA[g].y;
        Z += __shfl_xor(Z, 16); Z += __shfl_xor(Z, 32);
        A += __shfl_xor(A, 16); A += __shfl_xor(A, 32);
        if (lg == 0)
            P2[((size_t)ks << 14) + ((size_t)b << 12) + q0 + g * 64 + wid * 16 + ll] =
                make_float2(Z, A);
    }
}

// ---------------------------------------------------------------------------
// Kernel 3: sum KS additive partials, sigmoid(A/Z + bo). 256 blocks x 64.
// ---------------------------------------------------------------------------
__global__ __launch_bounds__(64) void combine_kernel(
    const float2* __restrict__ P2, const float* __restrict__ bo,
    float* __restrict__ out)
{
    int i = blockIdx.x * 64 + threadIdx.x;     // NB*NN = 16384
    float Z = 0.f, A = 0.f;
    #pragma unroll
    for (int r = 0; r < KS; ++r) {
        float2 p = P2[((size_t)r << 14) + i];
        Z += p.x; A += p.y;
    }
    float y = A / Z + bo[0];
    out[i] = 1.f / (1.f + __expf(-y));
}

extern "C" void kernel_launch(void* const* d_in, const int* in_sizes, int n_in,
                              void* d_out, int out_size, void* d_ws, size_t ws_size,
                              hipStream_t stream)
{
    const float* x  = (const float*)d_in[0];
    const float* Wq = (const float*)d_in[1];
    const float* bq = (const float*)d_in[2];
    const float* Wk = (const float*)d_in[3];
    const float* bk = (const float*)d_in[4];
    const float* Wv = (const float*)d_in[5];
    const float* bv = (const float*)d_in[6];
    const float* Wo = (const float*)d_in[7];
    const float* bo = (const float*)d_in[8];
    float* out = (float*)d_out;

    unsigned short* Qb = (unsigned short*)d_ws;            // 2 MB
    unsigned short* Kb = Qb + (size_t)NB * NN * 64;        // 2 MB
    float* VW = (float*)(Kb + (size_t)NB * NN * 64);       // 64 KB
    float2* P2 = (float2*)(VW + (size_t)NB * NN);          // 2 MB

    prep_mfma<<<NB * 128, 256, 0, stream>>>(x, Wq, bq, Wk, bk, Wv, bv, Wo,
                                            Qb, Kb, VW);
    attn_mfma<<<NQT * KS, 256, 0, stream>>>(Qb, Kb, VW, P2);
    combine_kernel<<<(NB * NN) / 64, 64, 0, stream>>>(P2, bo, out);
}